// Round 1
// baseline (3303.373 us; speedup 1.0000x reference)
//
#include <hip/hip_runtime.h>

#define DIM 128
#define NOUT 40
#define ROWS 64   // nodes per GEMM block

// -------- scatter-add: agg[dst[e]] += x[src[e]], 32 lanes per edge --------
__global__ __launch_bounds__(256) void scatter_kernel(
    const float* __restrict__ x,
    const int* __restrict__ src, const int* __restrict__ dst,
    float* __restrict__ agg, int n_edges)
{
    int idx  = blockIdx.x * 256 + threadIdx.x;
    int e    = idx >> 5;
    int lane = idx & 31;
    if (e >= n_edges) return;
    int s = src[e];
    int d = dst[e];
    float4 v = reinterpret_cast<const float4*>(x + (size_t)s * DIM)[lane];
    float* o = agg + (size_t)d * DIM + lane * 4;
    atomicAdd(o + 0, v.x);
    atomicAdd(o + 1, v.y);
    atomicAdd(o + 2, v.z);
    atomicAdd(o + 3, v.w);
}

// -------- layer GEMM: y = ((1+eps)*x + agg) @ W + b --------
// W is [k][n] row-major 128x128. Two 64-k LDS panels keep LDS at ~66KB (2 blocks/CU).
__global__ __launch_bounds__(256) void gin_layer_gemm(
    const float* __restrict__ xin, const float* __restrict__ agg,
    const float* __restrict__ W, const float* __restrict__ bias,
    const float* __restrict__ eps, int layer,
    float* __restrict__ y, int n_nodes)
{
    __shared__ float Wl[64 * DIM];        // one 64-k panel of W, [k][n]
    __shared__ float Hl[ROWS][DIM + 4];   // padded rows (stride 132 floats, 16B aligned)

    const int t  = threadIdx.x;
    const int r0 = blockIdx.x * ROWS;
    const float e1 = 1.0f + eps[layer];

    // stage H = (1+eps)*x + agg  (8 rows in flight, float4 per lane)
    {
        int c4 = t & 31;
        for (int rr = t >> 5; rr < ROWS; rr += 8) {
            int r = r0 + rr;
            float4 v = make_float4(0.f, 0.f, 0.f, 0.f);
            if (r < n_nodes) {
                float4 xv = reinterpret_cast<const float4*>(xin + (size_t)r * DIM)[c4];
                float4 av = reinterpret_cast<const float4*>(agg + (size_t)r * DIM)[c4];
                v = make_float4(e1 * xv.x + av.x, e1 * xv.y + av.y,
                                e1 * xv.z + av.z, e1 * xv.w + av.w);
            }
            reinterpret_cast<float4*>(&Hl[rr][0])[c4] = v;
        }
    }

    const int rg = t >> 4;   // 0..15 -> rows rg*4..rg*4+3
    const int cg = t & 15;   // 0..15 -> cols cg*8..cg*8+7
    float acc[4][8];
    #pragma unroll
    for (int i = 0; i < 4; ++i)
        #pragma unroll
        for (int j = 0; j < 8; ++j) acc[i][j] = 0.f;

    for (int kt = 0; kt < 2; ++kt) {
        __syncthreads();   // Hl ready (kt=0) / previous panel consumed (kt=1)
        // stage W panel [kt*64 .. kt*64+63][:]  (2048 float4 / 256 threads)
        {
            const float4* W4 = reinterpret_cast<const float4*>(W + (size_t)kt * 64 * DIM);
            float4* Wl4 = reinterpret_cast<float4*>(Wl);
            #pragma unroll
            for (int i = 0; i < 8; ++i) Wl4[t + i * 256] = W4[t + i * 256];
        }
        __syncthreads();

        const int kbase = kt * 64;
        #pragma unroll 4
        for (int k = 0; k < 64; ++k) {
            float4 w0 = reinterpret_cast<float4*>(&Wl[k * DIM])[cg * 2];
            float4 w1 = reinterpret_cast<float4*>(&Wl[k * DIM])[cg * 2 + 1];
            float h0 = Hl[rg * 4 + 0][kbase + k];
            float h1 = Hl[rg * 4 + 1][kbase + k];
            float h2 = Hl[rg * 4 + 2][kbase + k];
            float h3 = Hl[rg * 4 + 3][kbase + k];
            #pragma unroll
            for (int i = 0; i < 4; ++i) {
                float h = (i == 0) ? h0 : (i == 1) ? h1 : (i == 2) ? h2 : h3;
                acc[i][0] += h * w0.x;  acc[i][1] += h * w0.y;
                acc[i][2] += h * w0.z;  acc[i][3] += h * w0.w;
                acc[i][4] += h * w1.x;  acc[i][5] += h * w1.y;
                acc[i][6] += h * w1.z;  acc[i][7] += h * w1.w;
            }
        }
    }

    // store with bias, float4 x2 per row
    float4 b0 = reinterpret_cast<const float4*>(bias)[cg * 2];
    float4 b1 = reinterpret_cast<const float4*>(bias)[cg * 2 + 1];
    #pragma unroll
    for (int i = 0; i < 4; ++i) {
        int r = r0 + rg * 4 + i;
        if (r < n_nodes) {
            float4* out = reinterpret_cast<float4*>(y + (size_t)r * DIM + cg * 8);
            out[0] = make_float4(acc[i][0] + b0.x, acc[i][1] + b0.y,
                                 acc[i][2] + b0.z, acc[i][3] + b0.w);
            out[1] = make_float4(acc[i][4] + b1.x, acc[i][5] + b1.y,
                                 acc[i][6] + b1.z, acc[i][7] + b1.w);
        }
    }
}

// -------- head GEMM: out = x @ W_head + b_head  (128 -> 40) --------
__global__ __launch_bounds__(256) void head_gemm(
    const float* __restrict__ xin, const float* __restrict__ W,
    const float* __restrict__ bias, float* __restrict__ y, int n_nodes)
{
    __shared__ float Wl[DIM * NOUT];      // [k][n] 20KB
    __shared__ float Hl[ROWS][DIM + 4];   // 33.8KB

    const int t  = threadIdx.x;
    const int r0 = blockIdx.x * ROWS;

    for (int i = t; i < DIM * NOUT; i += 256) Wl[i] = W[i];
    {
        int c4 = t & 31;
        for (int rr = t >> 5; rr < ROWS; rr += 8) {
            int r = r0 + rr;
            float4 v = make_float4(0.f, 0.f, 0.f, 0.f);
            if (r < n_nodes)
                v = reinterpret_cast<const float4*>(xin + (size_t)r * DIM)[c4];
            reinterpret_cast<float4*>(&Hl[rr][0])[c4] = v;
        }
    }
    __syncthreads();

    const int row = t >> 2;          // 0..63
    const int cg  = (t & 3) * 10;    // 0,10,20,30
    float acc[10];
    #pragma unroll
    for (int j = 0; j < 10; ++j) acc[j] = 0.f;

    #pragma unroll 4
    for (int k = 0; k < DIM; ++k) {
        float h = Hl[row][k];
        #pragma unroll
        for (int j = 0; j < 10; ++j) acc[j] += h * Wl[k * NOUT + cg + j];
    }

    int r = r0 + row;
    if (r < n_nodes) {
        float* out = y + (size_t)r * NOUT + cg;
        #pragma unroll
        for (int j = 0; j < 10; ++j) out[j] = acc[j] + bias[cg + j];
    }
}

extern "C" void kernel_launch(void* const* d_in, const int* in_sizes, int n_in,
                              void* d_out, int out_size, void* d_ws, size_t ws_size,
                              hipStream_t stream) {
    (void)n_in; (void)out_size; (void)ws_size;
    const float* x    = (const float*)d_in[0];
    const int*   edge = (const int*)d_in[1];
    const float* eps  = (const float*)d_in[2];
    const float* Ws   = (const float*)d_in[3];
    const float* bs   = (const float*)d_in[4];
    const float* Wh   = (const float*)d_in[5];
    const float* bh   = (const float*)d_in[6];

    const int n_nodes = in_sizes[0] / DIM;
    const int n_edges = in_sizes[1] / 2;
    const int* src = edge;
    const int* dst = edge + n_edges;

    float* bufA = (float*)d_ws;                          // current features (51.2 MB)
    float* bufB = bufA + (size_t)n_nodes * DIM;          // agg scratch   (51.2 MB)

    const dim3 blk(256);
    const int scatter_grid = (n_edges * 32 + 255) / 256;
    const int gemm_grid    = (n_nodes + ROWS - 1) / ROWS;

    const float* cur = x;
    for (int l = 0; l < 3; ++l) {
        hipMemsetAsync(bufB, 0, (size_t)n_nodes * DIM * sizeof(float), stream);
        scatter_kernel<<<scatter_grid, blk, 0, stream>>>(cur, src, dst, bufB, n_edges);
        gin_layer_gemm<<<gemm_grid, blk, 0, stream>>>(
            cur, bufB, Ws + (size_t)l * DIM * DIM, bs + (size_t)l * DIM,
            eps, l, bufA, n_nodes);
        cur = bufA;   // in-place x->x is safe: each block only touches its own 64 rows
    }
    head_gemm<<<gemm_grid, blk, 0, stream>>>(bufA, Wh, bh, (float*)d_out, n_nodes);
}

// Round 2
// 615.004 us; speedup vs baseline: 5.3713x; 5.3713x over previous
//
#include <hip/hip_runtime.h>

#define DIM 128
#define NOUT 40
#define ROWS 64   // nodes per GEMM block

// ============ CSR build (once per launch; edge_index shared by all layers) ============

__global__ __launch_bounds__(256) void hist_kernel(
    const int* __restrict__ dst, int* __restrict__ deg, int n_edges)
{
    int e = blockIdx.x * 256 + threadIdx.x;
    if (e < n_edges) atomicAdd(&deg[dst[e]], 1);
}

// single-block exclusive scan over n (=100000) degrees -> offsets[0..n]
__global__ __launch_bounds__(1024) void scan_kernel(
    const int* __restrict__ deg, int* __restrict__ off, int n)
{
    __shared__ int lds[1024];
    int t = threadIdx.x;
    int chunk = (n + 1023) >> 10;
    int beg = t * chunk;
    int end = min(beg + chunk, n);
    int s = 0;
    for (int i = beg; i < end; ++i) s += deg[i];
    lds[t] = s;
    __syncthreads();
    for (int d = 1; d < 1024; d <<= 1) {   // Hillis-Steele inclusive scan
        int v = (t >= d) ? lds[t - d] : 0;
        __syncthreads();
        lds[t] += v;
        __syncthreads();
    }
    int prefix = lds[t] - s;               // exclusive
    for (int i = beg; i < end; ++i) { off[i] = prefix; prefix += deg[i]; }
    if (t == 1023) off[n] = lds[1023];
}

// bucket-fill: csr_src[off[dst[e]] + slot] = src[e]
__global__ __launch_bounds__(256) void fill_kernel(
    const int* __restrict__ src, const int* __restrict__ dst,
    const int* __restrict__ off, int* __restrict__ cursor,
    int* __restrict__ csr_src, int n_edges)
{
    int e = blockIdx.x * 256 + threadIdx.x;
    if (e >= n_edges) return;
    int d = dst[e];
    int pos = off[d] + atomicAdd(&cursor[d], 1);
    csr_src[pos] = src[e];
}

// ============ gather-aggregate: agg[i] = sum_{e in bucket(i)} x[csr_src[e]] ============
// one 64-lane wave per node, float2 per lane (512 B/row coalesced); 2-edge unroll for MLP
__global__ __launch_bounds__(256) void aggregate_kernel(
    const float* __restrict__ x, const int* __restrict__ csr_src,
    const int* __restrict__ off, float* __restrict__ agg, int n_nodes)
{
    int node = blockIdx.x * 4 + (threadIdx.x >> 6);
    if (node >= n_nodes) return;
    int lane = threadIdx.x & 63;
    int beg = off[node], end = off[node + 1];
    float2 acc = make_float2(0.f, 0.f);
    int k = beg;
    for (; k + 1 < end; k += 2) {
        int s0 = csr_src[k], s1 = csr_src[k + 1];
        float2 v0 = reinterpret_cast<const float2*>(x + (size_t)s0 * DIM)[lane];
        float2 v1 = reinterpret_cast<const float2*>(x + (size_t)s1 * DIM)[lane];
        acc.x += v0.x + v1.x;
        acc.y += v0.y + v1.y;
    }
    if (k < end) {
        int s0 = csr_src[k];
        float2 v0 = reinterpret_cast<const float2*>(x + (size_t)s0 * DIM)[lane];
        acc.x += v0.x;
        acc.y += v0.y;
    }
    reinterpret_cast<float2*>(agg + (size_t)node * DIM)[lane] = acc;
}

// ============ layer GEMM: y = ((1+eps)*x + agg) @ W + b ============
__global__ __launch_bounds__(256) void gin_layer_gemm(
    const float* __restrict__ xin, const float* __restrict__ agg,
    const float* __restrict__ W, const float* __restrict__ bias,
    const float* __restrict__ eps, int layer,
    float* __restrict__ y, int n_nodes)
{
    __shared__ float Wl[64 * DIM];        // one 64-k panel of W, [k][n]
    __shared__ float Hl[ROWS][DIM + 4];

    const int t  = threadIdx.x;
    const int r0 = blockIdx.x * ROWS;
    const float e1 = 1.0f + eps[layer];

    {
        int c4 = t & 31;
        for (int rr = t >> 5; rr < ROWS; rr += 8) {
            int r = r0 + rr;
            float4 v = make_float4(0.f, 0.f, 0.f, 0.f);
            if (r < n_nodes) {
                float4 xv = reinterpret_cast<const float4*>(xin + (size_t)r * DIM)[c4];
                float4 av = reinterpret_cast<const float4*>(agg + (size_t)r * DIM)[c4];
                v = make_float4(e1 * xv.x + av.x, e1 * xv.y + av.y,
                                e1 * xv.z + av.z, e1 * xv.w + av.w);
            }
            reinterpret_cast<float4*>(&Hl[rr][0])[c4] = v;
        }
    }

    const int rg = t >> 4;
    const int cg = t & 15;
    float acc[4][8];
    #pragma unroll
    for (int i = 0; i < 4; ++i)
        #pragma unroll
        for (int j = 0; j < 8; ++j) acc[i][j] = 0.f;

    for (int kt = 0; kt < 2; ++kt) {
        __syncthreads();
        {
            const float4* W4 = reinterpret_cast<const float4*>(W + (size_t)kt * 64 * DIM);
            float4* Wl4 = reinterpret_cast<float4*>(Wl);
            #pragma unroll
            for (int i = 0; i < 8; ++i) Wl4[t + i * 256] = W4[t + i * 256];
        }
        __syncthreads();

        const int kbase = kt * 64;
        #pragma unroll 4
        for (int k = 0; k < 64; ++k) {
            float4 w0 = reinterpret_cast<float4*>(&Wl[k * DIM])[cg * 2];
            float4 w1 = reinterpret_cast<float4*>(&Wl[k * DIM])[cg * 2 + 1];
            float h0 = Hl[rg * 4 + 0][kbase + k];
            float h1 = Hl[rg * 4 + 1][kbase + k];
            float h2 = Hl[rg * 4 + 2][kbase + k];
            float h3 = Hl[rg * 4 + 3][kbase + k];
            #pragma unroll
            for (int i = 0; i < 4; ++i) {
                float h = (i == 0) ? h0 : (i == 1) ? h1 : (i == 2) ? h2 : h3;
                acc[i][0] += h * w0.x;  acc[i][1] += h * w0.y;
                acc[i][2] += h * w0.z;  acc[i][3] += h * w0.w;
                acc[i][4] += h * w1.x;  acc[i][5] += h * w1.y;
                acc[i][6] += h * w1.z;  acc[i][7] += h * w1.w;
            }
        }
    }

    float4 b0 = reinterpret_cast<const float4*>(bias)[cg * 2];
    float4 b1 = reinterpret_cast<const float4*>(bias)[cg * 2 + 1];
    #pragma unroll
    for (int i = 0; i < 4; ++i) {
        int r = r0 + rg * 4 + i;
        if (r < n_nodes) {
            float4* out = reinterpret_cast<float4*>(y + (size_t)r * DIM + cg * 8);
            out[0] = make_float4(acc[i][0] + b0.x, acc[i][1] + b0.y,
                                 acc[i][2] + b0.z, acc[i][3] + b0.w);
            out[1] = make_float4(acc[i][4] + b1.x, acc[i][5] + b1.y,
                                 acc[i][6] + b1.z, acc[i][7] + b1.w);
        }
    }
}

// ============ head GEMM: out = x @ W_head + b_head (128 -> 40) ============
__global__ __launch_bounds__(256) void head_gemm(
    const float* __restrict__ xin, const float* __restrict__ W,
    const float* __restrict__ bias, float* __restrict__ y, int n_nodes)
{
    __shared__ float Wl[DIM * NOUT];
    __shared__ float Hl[ROWS][DIM + 4];

    const int t  = threadIdx.x;
    const int r0 = blockIdx.x * ROWS;

    for (int i = t; i < DIM * NOUT; i += 256) Wl[i] = W[i];
    {
        int c4 = t & 31;
        for (int rr = t >> 5; rr < ROWS; rr += 8) {
            int r = r0 + rr;
            float4 v = make_float4(0.f, 0.f, 0.f, 0.f);
            if (r < n_nodes)
                v = reinterpret_cast<const float4*>(xin + (size_t)r * DIM)[c4];
            reinterpret_cast<float4*>(&Hl[rr][0])[c4] = v;
        }
    }
    __syncthreads();

    const int row = t >> 2;
    const int cg  = (t & 3) * 10;
    float acc[10];
    #pragma unroll
    for (int j = 0; j < 10; ++j) acc[j] = 0.f;

    #pragma unroll 4
    for (int k = 0; k < DIM; ++k) {
        float h = Hl[row][k];
        #pragma unroll
        for (int j = 0; j < 10; ++j) acc[j] += h * Wl[k * NOUT + cg + j];
    }

    int r = r0 + row;
    if (r < n_nodes) {
        float* out = y + (size_t)r * NOUT + cg;
        #pragma unroll
        for (int j = 0; j < 10; ++j) out[j] = acc[j] + bias[cg + j];
    }
}

extern "C" void kernel_launch(void* const* d_in, const int* in_sizes, int n_in,
                              void* d_out, int out_size, void* d_ws, size_t ws_size,
                              hipStream_t stream) {
    (void)n_in; (void)out_size;
    const float* x    = (const float*)d_in[0];
    const int*   edge = (const int*)d_in[1];
    const float* eps  = (const float*)d_in[2];
    const float* Ws   = (const float*)d_in[3];
    const float* bs   = (const float*)d_in[4];
    const float* Wh   = (const float*)d_in[5];
    const float* bh   = (const float*)d_in[6];

    const int n_nodes = in_sizes[0] / DIM;
    const int n_edges = in_sizes[1] / 2;
    const int* src = edge;
    const int* dst = edge + n_edges;

    const size_t featB = (size_t)n_nodes * DIM * sizeof(float);
    float* bufA = (float*)d_ws;                       // features ping buffer
    float* bufB = (float*)((char*)d_ws + featB);      // agg buffer

    // CSR scratch: deg/cursor (n), offsets (n+1), csr_src (E) = ~3.2 MB.
    // Prefer tail of d_ws; fall back to d_out (16 MB, overwritten by head at the end).
    const size_t extraB = ((size_t)n_nodes + (size_t)(n_nodes + 1) + (size_t)n_edges) * sizeof(int);
    char* extra = (ws_size >= 2 * featB + extraB)
                ? (char*)d_ws + 2 * featB
                : (char*)d_out;
    int* deg = (int*)extra;                 // reused as fill-cursor after scan
    int* off = deg + n_nodes;
    int* csr = off + n_nodes + 1;

    const dim3 blk(256);
    const int edge_grid = (n_edges + 255) / 256;
    const int gemm_grid = (n_nodes + ROWS - 1) / ROWS;
    const int agg_grid  = (n_nodes + 3) / 4;

    // ---- build CSR once ----
    hipMemsetAsync(deg, 0, (size_t)n_nodes * sizeof(int), stream);
    hist_kernel<<<edge_grid, blk, 0, stream>>>(dst, deg, n_edges);
    scan_kernel<<<1, 1024, 0, stream>>>(deg, off, n_nodes);
    hipMemsetAsync(deg, 0, (size_t)n_nodes * sizeof(int), stream);
    fill_kernel<<<edge_grid, blk, 0, stream>>>(src, dst, off, deg, csr, n_edges);

    // ---- 3 GIN layers ----
    const float* cur = x;
    for (int l = 0; l < 3; ++l) {
        aggregate_kernel<<<agg_grid, blk, 0, stream>>>(cur, csr, off, bufB, n_nodes);
        gin_layer_gemm<<<gemm_grid, blk, 0, stream>>>(
            cur, bufB, Ws + (size_t)l * DIM * DIM, bs + (size_t)l * DIM,
            eps, l, bufA, n_nodes);
        cur = bufA;
    }
    head_gemm<<<gemm_grid, blk, 0, stream>>>(bufA, Wh, bh, (float*)d_out, n_nodes);
}